// Round 1
// baseline (350.745 us; speedup 1.0000x reference)
//
#include <hip/hip_runtime.h>

// Problem: B=32, C=17, H=256, W=256 fp32.
// out = 0.5 * ( sum(m1?d:0)/sum(m1) + sum(m2?d:0)/(sum(m2)*C) )
//   m1 = target>0 per element; m2 = any(m1 over C) per (b,h,w); d = |input-target|.

#define QPB      16384                  // (H*W)/4 float4-quads per (b,c) plane
#define N_CH     17
#define N_BATCH  32
#define N_QUADS  (N_BATCH * QPB)        // 524288 pixel-quads
#define N_BLOCKS 2048                   // one quad per thread
#define PF       8                      // channel-pair prefetch depth (16 loads in flight)

struct Slot {
    float s1;
    float s2;
    unsigned int c1;
    unsigned int c2;
};

// Stage 1: one thread = one pixel-quad; 17 channels through a depth-8
// software-pipelined ring (t,x pairs) so ~16 global_load_dwordx4 stay in
// flight per thread.
//
// launch_bounds(256, 4): 128-VGPR budget. The previous build used (256, 8)
// (64-VGPR cap) and the compiler COLLAPSED the prefetch ring to fit —
// VGPR_Count came back 24, i.e. ~1 pair in flight, and the kernel ran
// latency-bound at 2.8 TB/s effective. 16 waves/CU with 16 deep loads per
// thread is the better point for a pure-streaming kernel.
__global__ __launch_bounds__(256, 4) void heatloss_stage1(
    const float* __restrict__ inp, const float* __restrict__ tgt,
    Slot* __restrict__ slots) {

    // Blocks are assigned to XCDs round-robin (xcd = blockIdx % 8). Remap so
    // each XCD sweeps one contiguous range of q — L3/DRAM-channel locality.
    const int blk = (blockIdx.x & 7) * (N_BLOCKS / 8) + (blockIdx.x >> 3);
    const int q = blk * 256 + threadIdx.x;
    const int b = q >> 14;                          // q / QPB
    const int r = q & (QPB - 1);                    // q % QPB

    const float4* __restrict__ tp = (const float4*)tgt + (size_t)b * (N_CH * QPB) + r;
    const float4* __restrict__ xp = (const float4*)inp + (size_t)b * (N_CH * QPB) + r;

    float4 tb[PF], xb[PF];
    #pragma unroll
    for (int i = 0; i < PF; ++i) {
        tb[i] = tp[(size_t)i * QPB];
        xb[i] = xp[(size_t)i * QPB];
    }

    float s1 = 0.0f;
    unsigned int c1 = 0u;
    float sa0 = 0.f, sa1 = 0.f, sa2 = 0.f, sa3 = 0.f;
    bool a0 = false, a1 = false, a2 = false, a3 = false;

    #pragma unroll
    for (int c = 0; c < N_CH; ++c) {
        const int slot = c % PF;                     // compile-time (full unroll)
        float4 t = tb[slot];
        float4 x = xb[slot];
        if (c + PF < N_CH) {                         // refill ring slot
            tb[slot] = tp[(size_t)(c + PF) * QPB];
            xb[slot] = xp[(size_t)(c + PF) * QPB];
        }
        float d0 = fabsf(x.x - t.x);
        float d1 = fabsf(x.y - t.y);
        float d2 = fabsf(x.z - t.z);
        float d3 = fabsf(x.w - t.w);
        bool p0 = t.x > 0.f, p1 = t.y > 0.f, p2 = t.z > 0.f, p3 = t.w > 0.f;
        sa0 += d0; sa1 += d1; sa2 += d2; sa3 += d3;
        s1 += p0 ? d0 : 0.f;  c1 += p0 ? 1u : 0u;  a0 = a0 || p0;
        s1 += p1 ? d1 : 0.f;  c1 += p1 ? 1u : 0u;  a1 = a1 || p1;
        s1 += p2 ? d2 : 0.f;  c1 += p2 ? 1u : 0u;  a2 = a2 || p2;
        s1 += p3 ? d3 : 0.f;  c1 += p3 ? 1u : 0u;  a3 = a3 || p3;
    }
    float s2 = (a0 ? sa0 : 0.f) + (a1 ? sa1 : 0.f) + (a2 ? sa2 : 0.f) + (a3 ? sa3 : 0.f);
    unsigned int c2 = (a0 ? 1u : 0u) + (a1 ? 1u : 0u) + (a2 ? 1u : 0u) + (a3 ? 1u : 0u);

    // Intra-wave butterfly reduction (wave = 64 on gfx950)
    #pragma unroll
    for (int off = 32; off > 0; off >>= 1) {
        s1 += __shfl_down(s1, off);
        s2 += __shfl_down(s2, off);
        c1 += __shfl_down(c1, off);
        c2 += __shfl_down(c2, off);
    }

    __shared__ float ls1[4], ls2[4];
    __shared__ unsigned int lc1[4], lc2[4];
    const int wave = threadIdx.x >> 6;
    const int lane = threadIdx.x & 63;
    if (lane == 0) {
        ls1[wave] = s1; ls2[wave] = s2;
        lc1[wave] = c1; lc2[wave] = c2;
    }
    __syncthreads();
    if (threadIdx.x == 0) {
        Slot sl;
        sl.s1 = ls1[0] + ls1[1] + ls1[2] + ls1[3];
        sl.s2 = ls2[0] + ls2[1] + ls2[2] + ls2[3];
        sl.c1 = lc1[0] + lc1[1] + lc1[2] + lc1[3];
        sl.c2 = lc2[0] + lc2[1] + lc2[2] + lc2[3];
        slots[blockIdx.x] = sl;   // private slot — no contention
    }
}

// Stage 2: one block sums the 2048 per-block slots (counts summed exactly as
// uints) and writes the final scalar.
__global__ __launch_bounds__(256) void heatloss_stage2(
    const Slot* __restrict__ slots, float* __restrict__ out) {

    float s1 = 0.f, s2 = 0.f;
    unsigned int c1 = 0u, c2 = 0u;
    for (int i = threadIdx.x; i < N_BLOCKS; i += 256) {
        Slot sl = slots[i];
        s1 += sl.s1; s2 += sl.s2; c1 += sl.c1; c2 += sl.c2;
    }
    #pragma unroll
    for (int off = 32; off > 0; off >>= 1) {
        s1 += __shfl_down(s1, off);
        s2 += __shfl_down(s2, off);
        c1 += __shfl_down(c1, off);
        c2 += __shfl_down(c2, off);
    }
    __shared__ float ls1[4], ls2[4];
    __shared__ unsigned int lc1[4], lc2[4];
    const int wave = threadIdx.x >> 6;
    const int lane = threadIdx.x & 63;
    if (lane == 0) {
        ls1[wave] = s1; ls2[wave] = s2;
        lc1[wave] = c1; lc2[wave] = c2;
    }
    __syncthreads();
    if (threadIdx.x == 0) {
        float S1 = ls1[0] + ls1[1] + ls1[2] + ls1[3];
        float S2 = ls2[0] + ls2[1] + ls2[2] + ls2[3];
        float C1 = (float)(lc1[0] + lc1[1] + lc1[2] + lc1[3]);
        float C2 = (float)(lc2[0] + lc2[1] + lc2[2] + lc2[3]);
        float mean1 = S1 / C1;
        float mean2 = S2 / (C2 * (float)N_CH);
        out[0] = 0.5f * (mean1 + mean2);
    }
}

extern "C" void kernel_launch(void* const* d_in, const int* in_sizes, int n_in,
                              void* d_out, int out_size, void* d_ws, size_t ws_size,
                              hipStream_t stream) {
    const float* inp = (const float*)d_in[0];
    const float* tgt = (const float*)d_in[1];
    // d_in[2] (masks) and d_in[3] (hull) are unused by the forward pass.
    float* out = (float*)d_out;
    Slot* slots = (Slot*)d_ws;   // 2048 * 16 B = 32 KB scratch

    heatloss_stage1<<<N_BLOCKS, 256, 0, stream>>>(inp, tgt, slots);
    heatloss_stage2<<<1, 256, 0, stream>>>(slots, out);
}

// Round 2
// 346.767 us; speedup vs baseline: 1.0115x; 1.0115x over previous
//
#include <hip/hip_runtime.h>

// Problem: B=32, C=17, H=256, W=256 fp32.
// out = 0.5 * ( sum(m1?d:0)/sum(m1) + sum(m2?d:0)/(sum(m2)*C) )
//   m1 = target>0 per element; m2 = any(m1 over C) per (b,h,w); d = |input-target|.

#define QPB      16384                  // (H*W)/4 float4-quads per (b,c) plane
#define N_CH     17
#define N_BATCH  32
#define N_QUADS  (N_BATCH * QPB)        // 524288 pixel-quads
#define N_BLOCKS 2048                   // one quad per thread

struct Slot {
    float s1;
    float s2;
    unsigned int c1;
    unsigned int c2;
};

// Stage 1 — MLP-decisive experiment.
//
// Rounds 0/1 showed the compiler collapses any software-pipelined prefetch
// ring (PF=3 -> VGPR 24, PF=8 -> VGPR 48): pre-RA scheduling sinks loads to
// their consumers to minimize pressure, so in-flight depth never grows and
// the kernel sits at 2.74 TB/s effective (45% of streaming ceiling).
//
// This version loads ALL 17 channel-pairs (34 global_load_dwordx4, 136 data
// VGPRs) before any consumption, with sched_barrier(0) as a fence the
// scheduler cannot cross. 34 KB in flight per wave guarantees the
// latency-hiding regime even at reduced occupancy. If this doesn't move the
// duration, the access pattern (34 strided 1-KB streams per wave) is the
// memory-system cap and the next step is restructuring the pattern, not the
// schedule.
__global__ __launch_bounds__(256) void heatloss_stage1(
    const float* __restrict__ inp, const float* __restrict__ tgt,
    Slot* __restrict__ slots) {

    // Blocks are assigned to XCDs round-robin (xcd = blockIdx % 8). Remap so
    // each XCD sweeps one contiguous range of q — L3/DRAM-channel locality.
    const int blk = (blockIdx.x & 7) * (N_BLOCKS / 8) + (blockIdx.x >> 3);
    const int q = blk * 256 + threadIdx.x;
    const int b = q >> 14;                          // q / QPB
    const int r = q & (QPB - 1);                    // q % QPB

    const float4* __restrict__ tp = (const float4*)tgt + (size_t)b * (N_CH * QPB) + r;
    const float4* __restrict__ xp = (const float4*)inp + (size_t)b * (N_CH * QPB) + r;

    // ---- load section: 34 independent global_load_dwordx4, no consumers ----
    float4 tb[N_CH], xb[N_CH];
    #pragma unroll
    for (int c = 0; c < N_CH; ++c) tb[c] = tp[(size_t)c * QPB];
    #pragma unroll
    for (int c = 0; c < N_CH; ++c) xb[c] = xp[(size_t)c * QPB];

    // Fence: nothing from below may be hoisted above, nothing from above may
    // be sunk below. Forces all 34 loads to issue before the first waitcnt.
    __builtin_amdgcn_sched_barrier(0);

    // ---- compute section ----
    float s1 = 0.0f;
    unsigned int c1 = 0u;
    float sa0 = 0.f, sa1 = 0.f, sa2 = 0.f, sa3 = 0.f;
    bool a0 = false, a1 = false, a2 = false, a3 = false;

    #pragma unroll
    for (int c = 0; c < N_CH; ++c) {
        float4 t = tb[c];
        float4 x = xb[c];
        float d0 = fabsf(x.x - t.x);
        float d1 = fabsf(x.y - t.y);
        float d2 = fabsf(x.z - t.z);
        float d3 = fabsf(x.w - t.w);
        bool p0 = t.x > 0.f, p1 = t.y > 0.f, p2 = t.z > 0.f, p3 = t.w > 0.f;
        sa0 += d0; sa1 += d1; sa2 += d2; sa3 += d3;
        s1 += p0 ? d0 : 0.f;  c1 += p0 ? 1u : 0u;  a0 = a0 || p0;
        s1 += p1 ? d1 : 0.f;  c1 += p1 ? 1u : 0u;  a1 = a1 || p1;
        s1 += p2 ? d2 : 0.f;  c1 += p2 ? 1u : 0u;  a2 = a2 || p2;
        s1 += p3 ? d3 : 0.f;  c1 += p3 ? 1u : 0u;  a3 = a3 || p3;
    }
    float s2 = (a0 ? sa0 : 0.f) + (a1 ? sa1 : 0.f) + (a2 ? sa2 : 0.f) + (a3 ? sa3 : 0.f);
    unsigned int c2 = (a0 ? 1u : 0u) + (a1 ? 1u : 0u) + (a2 ? 1u : 0u) + (a3 ? 1u : 0u);

    // Intra-wave butterfly reduction (wave = 64 on gfx950)
    #pragma unroll
    for (int off = 32; off > 0; off >>= 1) {
        s1 += __shfl_down(s1, off);
        s2 += __shfl_down(s2, off);
        c1 += __shfl_down(c1, off);
        c2 += __shfl_down(c2, off);
    }

    __shared__ float ls1[4], ls2[4];
    __shared__ unsigned int lc1[4], lc2[4];
    const int wave = threadIdx.x >> 6;
    const int lane = threadIdx.x & 63;
    if (lane == 0) {
        ls1[wave] = s1; ls2[wave] = s2;
        lc1[wave] = c1; lc2[wave] = c2;
    }
    __syncthreads();
    if (threadIdx.x == 0) {
        Slot sl;
        sl.s1 = ls1[0] + ls1[1] + ls1[2] + ls1[3];
        sl.s2 = ls2[0] + ls2[1] + ls2[2] + ls2[3];
        sl.c1 = lc1[0] + lc1[1] + lc1[2] + lc1[3];
        sl.c2 = lc2[0] + lc2[1] + lc2[2] + lc2[3];
        slots[blockIdx.x] = sl;   // private slot — no contention
    }
}

// Stage 2: one block sums the 2048 per-block slots (counts summed exactly as
// uints) and writes the final scalar.
__global__ __launch_bounds__(256) void heatloss_stage2(
    const Slot* __restrict__ slots, float* __restrict__ out) {

    float s1 = 0.f, s2 = 0.f;
    unsigned int c1 = 0u, c2 = 0u;
    for (int i = threadIdx.x; i < N_BLOCKS; i += 256) {
        Slot sl = slots[i];
        s1 += sl.s1; s2 += sl.s2; c1 += sl.c1; c2 += sl.c2;
    }
    #pragma unroll
    for (int off = 32; off > 0; off >>= 1) {
        s1 += __shfl_down(s1, off);
        s2 += __shfl_down(s2, off);
        c1 += __shfl_down(c1, off);
        c2 += __shfl_down(c2, off);
    }
    __shared__ float ls1[4], ls2[4];
    __shared__ unsigned int lc1[4], lc2[4];
    const int wave = threadIdx.x >> 6;
    const int lane = threadIdx.x & 63;
    if (lane == 0) {
        ls1[wave] = s1; ls2[wave] = s2;
        lc1[wave] = c1; lc2[wave] = c2;
    }
    __syncthreads();
    if (threadIdx.x == 0) {
        float S1 = ls1[0] + ls1[1] + ls1[2] + ls1[3];
        float S2 = ls2[0] + ls2[1] + ls2[2] + ls2[3];
        float C1 = (float)(lc1[0] + lc1[1] + lc1[2] + lc1[3]);
        float C2 = (float)(lc2[0] + lc2[1] + lc2[2] + lc2[3]);
        float mean1 = S1 / C1;
        float mean2 = S2 / (C2 * (float)N_CH);
        out[0] = 0.5f * (mean1 + mean2);
    }
}

extern "C" void kernel_launch(void* const* d_in, const int* in_sizes, int n_in,
                              void* d_out, int out_size, void* d_ws, size_t ws_size,
                              hipStream_t stream) {
    const float* inp = (const float*)d_in[0];
    const float* tgt = (const float*)d_in[1];
    // d_in[2] (masks) and d_in[3] (hull) are unused by the forward pass.
    float* out = (float*)d_out;
    Slot* slots = (Slot*)d_ws;   // 2048 * 16 B = 32 KB scratch

    heatloss_stage1<<<N_BLOCKS, 256, 0, stream>>>(inp, tgt, slots);
    heatloss_stage2<<<1, 256, 0, stream>>>(slots, out);
}

// Round 3
// 339.163 us; speedup vs baseline: 1.0341x; 1.0224x over previous
//
#include <hip/hip_runtime.h>

// Problem: B=32, C=17, H=256, W=256 fp32.
// out = 0.5 * ( sum(m1?d:0)/sum(m1) + sum(m2?d:0)/(sum(m2)*C) )
//   m1 = target>0 per element; m2 = any(m1 over C) per (b,h,w); d = |input-target|.
//
// R0-R2 established: NOT latency/depth-bound (depth 2..12, occ 8..19 waves/CU
// all give 102-104 us, 2.77 TB/s effective; required in-flight is only ~9 KB/CU).
// Queueing arithmetic says a downstream resource saturates at ~2.77 TB/s for
// this 34-stream strided pattern. R3 tests the two pattern levers:
//   (a) 4x longer contiguous runs per stream-visit (G=4, c-major/g-minor),
//   (b) non-temporal loads (data is touched exactly once per dispatch; skip
//       L3/L2 retention entirely -> FETCH_SIZE should jump 139 -> ~285 MB).

#define QPB      16384                  // (H*W)/4 float4-quads per (b,c) plane
#define N_CH     17
#define N_BATCH  32
#define THREADS  256
#define G        4                      // quads per thread per channel
#define QUADS_PER_BLOCK (THREADS * G)   // 1024
#define BLK_PER_BATCH   (QPB / QUADS_PER_BLOCK)   // 16
#define N_BLOCKS (N_BATCH * BLK_PER_BATCH)        // 512

typedef float f32x4 __attribute__((ext_vector_type(4)));

struct Slot {
    float s1;
    float s2;
    unsigned int c1;
    unsigned int c2;
};

__device__ __forceinline__ f32x4 ntload(const f32x4* p) {
    return __builtin_nontemporal_load(p);
}

// Stage 1: each thread owns G=4 pixel-quad columns; channels looped c-major,
// quads g-minor, so each block's 4 waves collectively sweep one contiguous
// 16-KB extent per (array, channel) visit.
__global__ __launch_bounds__(256) void heatloss_stage1(
    const float* __restrict__ inp, const float* __restrict__ tgt,
    Slot* __restrict__ slots) {

    // XCD-contiguous remap (blocks round-robin XCDs; give each XCD one
    // contiguous q-range).
    const int blk = (blockIdx.x & 7) * (N_BLOCKS / 8) + (blockIdx.x >> 3);
    const int b  = blk >> 4;                               // / BLK_PER_BATCH
    const int rb = (blk & (BLK_PER_BATCH - 1)) * QUADS_PER_BLOCK;

    const size_t base = (size_t)b * (N_CH * QPB) + rb + threadIdx.x;
    const f32x4* __restrict__ tp = (const f32x4*)tgt + base;
    const f32x4* __restrict__ xp = (const f32x4*)inp + base;

    float s1 = 0.0f;
    unsigned int c1 = 0u;
    float sa[G][4];                 // per-pixel-column |d| sums across channels
    bool  an[G][4];                 // per-pixel-column any(t>0)
    #pragma unroll
    for (int g = 0; g < G; ++g)
        #pragma unroll
        for (int j = 0; j < 4; ++j) { sa[g][j] = 0.f; an[g][j] = false; }

    #pragma unroll
    for (int c = 0; c < N_CH; ++c) {
        #pragma unroll
        for (int g = 0; g < G; ++g) {
            const size_t off = (size_t)c * QPB + (size_t)g * THREADS;
            f32x4 t = ntload(tp + off);
            f32x4 x = ntload(xp + off);
            float d0 = fabsf(x.x - t.x);
            float d1 = fabsf(x.y - t.y);
            float d2 = fabsf(x.z - t.z);
            float d3 = fabsf(x.w - t.w);
            bool p0 = t.x > 0.f, p1 = t.y > 0.f, p2 = t.z > 0.f, p3 = t.w > 0.f;
            sa[g][0] += d0; sa[g][1] += d1; sa[g][2] += d2; sa[g][3] += d3;
            s1 += p0 ? d0 : 0.f;  c1 += p0 ? 1u : 0u;  an[g][0] = an[g][0] || p0;
            s1 += p1 ? d1 : 0.f;  c1 += p1 ? 1u : 0u;  an[g][1] = an[g][1] || p1;
            s1 += p2 ? d2 : 0.f;  c1 += p2 ? 1u : 0u;  an[g][2] = an[g][2] || p2;
            s1 += p3 ? d3 : 0.f;  c1 += p3 ? 1u : 0u;  an[g][3] = an[g][3] || p3;
        }
    }

    float s2 = 0.f;
    unsigned int c2 = 0u;
    #pragma unroll
    for (int g = 0; g < G; ++g) {
        #pragma unroll
        for (int j = 0; j < 4; ++j) {
            s2 += an[g][j] ? sa[g][j] : 0.f;
            c2 += an[g][j] ? 1u : 0u;
        }
    }

    // Intra-wave butterfly reduction (wave = 64 on gfx950)
    #pragma unroll
    for (int off = 32; off > 0; off >>= 1) {
        s1 += __shfl_down(s1, off);
        s2 += __shfl_down(s2, off);
        c1 += __shfl_down(c1, off);
        c2 += __shfl_down(c2, off);
    }

    __shared__ float ls1[4], ls2[4];
    __shared__ unsigned int lc1[4], lc2[4];
    const int wave = threadIdx.x >> 6;
    const int lane = threadIdx.x & 63;
    if (lane == 0) {
        ls1[wave] = s1; ls2[wave] = s2;
        lc1[wave] = c1; lc2[wave] = c2;
    }
    __syncthreads();
    if (threadIdx.x == 0) {
        Slot sl;
        sl.s1 = ls1[0] + ls1[1] + ls1[2] + ls1[3];
        sl.s2 = ls2[0] + ls2[1] + ls2[2] + ls2[3];
        sl.c1 = lc1[0] + lc1[1] + lc1[2] + lc1[3];
        sl.c2 = lc2[0] + lc2[1] + lc2[2] + lc2[3];
        slots[blockIdx.x] = sl;   // private slot — no contention
    }
}

// Stage 2: one block sums the 512 per-block slots (counts summed exactly as
// uints) and writes the final scalar.
__global__ __launch_bounds__(256) void heatloss_stage2(
    const Slot* __restrict__ slots, float* __restrict__ out) {

    float s1 = 0.f, s2 = 0.f;
    unsigned int c1 = 0u, c2 = 0u;
    for (int i = threadIdx.x; i < N_BLOCKS; i += 256) {
        Slot sl = slots[i];
        s1 += sl.s1; s2 += sl.s2; c1 += sl.c1; c2 += sl.c2;
    }
    #pragma unroll
    for (int off = 32; off > 0; off >>= 1) {
        s1 += __shfl_down(s1, off);
        s2 += __shfl_down(s2, off);
        c1 += __shfl_down(c1, off);
        c2 += __shfl_down(c2, off);
    }
    __shared__ float ls1[4], ls2[4];
    __shared__ unsigned int lc1[4], lc2[4];
    const int wave = threadIdx.x >> 6;
    const int lane = threadIdx.x & 63;
    if (lane == 0) {
        ls1[wave] = s1; ls2[wave] = s2;
        lc1[wave] = c1; lc2[wave] = c2;
    }
    __syncthreads();
    if (threadIdx.x == 0) {
        float S1 = ls1[0] + ls1[1] + ls1[2] + ls1[3];
        float S2 = ls2[0] + ls2[1] + ls2[2] + ls2[3];
        float C1 = (float)(lc1[0] + lc1[1] + lc1[2] + lc1[3]);
        float C2 = (float)(lc2[0] + lc2[1] + lc2[2] + lc2[3]);
        float mean1 = S1 / C1;
        float mean2 = S2 / (C2 * (float)N_CH);
        out[0] = 0.5f * (mean1 + mean2);
    }
}

extern "C" void kernel_launch(void* const* d_in, const int* in_sizes, int n_in,
                              void* d_out, int out_size, void* d_ws, size_t ws_size,
                              hipStream_t stream) {
    const float* inp = (const float*)d_in[0];
    const float* tgt = (const float*)d_in[1];
    // d_in[2] (masks) and d_in[3] (hull) are unused by the forward pass.
    float* out = (float*)d_out;
    Slot* slots = (Slot*)d_ws;   // 512 * 16 B = 8 KB scratch

    heatloss_stage1<<<N_BLOCKS, THREADS, 0, stream>>>(inp, tgt, slots);
    heatloss_stage2<<<1, 256, 0, stream>>>(slots, out);
}